// Round 6
// baseline (419.968 us; speedup 1.0000x reference)
//
#include <hip/hip_runtime.h>
#include <hip/hip_bf16.h>
#include <math.h>

// ---------------------------------------------------------------------------
// Transformer block. R5:
//  - GEMM: XCD-compact swizzle (each XCD = contiguous 4-M-tile band, A becomes
//    L2-resident, HBM A-fetch once) + distance-2 register prefetch (manual
//    2x unroll, two reg slots: tile t gloaded at iter t-3, ds_written t-1).
//  - Attention: double-buffered K/V LDS, ONE barrier/iter, K/V(kt+1) loaded
//    into regs right after the barrier and consumed a compute-phase later;
//    XCD swizzle gives each XCD 8 (b,h) pairs (2 MB K/V -> L2-resident).
// ---------------------------------------------------------------------------

#define TOKENS 4096
#define CDIM   1024
#define HEADS  16
#define DHEAD  64
#define HID    4096

typedef __attribute__((ext_vector_type(4))) float  floatx4;
typedef __attribute__((ext_vector_type(8))) short  short8;  // 8 x bf16 frag

// ---------------- fused fp32 -> bf16 weight convert ----------------
__global__ __launch_bounds__(256) void cvt_all(
    const float* __restrict__ s0, const float* __restrict__ s1,
    const float* __restrict__ s2, const float* __restrict__ s3,
    __hip_bfloat16* __restrict__ dst)
{
    long i = (long)blockIdx.x * 256 + threadIdx.x;   // float4 index, 3M total
    const float* src;
    long base;
    if (i < 768l * 1024)       { src = s0; base = 0; }
    else if (i < 1792l * 1024) { src = s1; base = 768l * 1024; }
    else if (i < 2816l * 1024) { src = s2; base = 1792l * 1024; }
    else                       { src = s3; base = 2816l * 1024; }
    float4 v = ((const float4*)src)[i - base];
    __hip_bfloat16 t[4];
    t[0] = __float2bfloat16(v.x);
    t[1] = __float2bfloat16(v.y);
    t[2] = __float2bfloat16(v.z);
    t[3] = __float2bfloat16(v.w);
    *(uint2*)(dst + 4l * i) = *(uint2*)t;
}

// ---------------- LayerNorm: fp32 in -> bf16 out ----------------
__global__ __launch_bounds__(256) void ln_f32_kernel(
    const float* __restrict__ x, const float* __restrict__ g,
    const float* __restrict__ b, __hip_bfloat16* __restrict__ y, int C)
{
    int row = blockIdx.x;
    const float* xr = x + (long)row * C;
    __hip_bfloat16* yr = y + (long)row * C;

    float s = 0.f, ss = 0.f;
    for (int i = threadIdx.x; i < C; i += 256) {
        float v = xr[i];
        s += v; ss += v * v;
    }
    #pragma unroll
    for (int d = 32; d; d >>= 1) {
        s  += __shfl_down(s, d);
        ss += __shfl_down(ss, d);
    }
    __shared__ float buf[4][2];
    int wid = threadIdx.x >> 6, lane = threadIdx.x & 63;
    if (lane == 0) { buf[wid][0] = s; buf[wid][1] = ss; }
    __syncthreads();
    if (threadIdx.x == 0) {
        s = buf[0][0] + buf[1][0] + buf[2][0] + buf[3][0];
        ss = buf[0][1] + buf[1][1] + buf[2][1] + buf[3][1];
        buf[0][0] = s; buf[0][1] = ss;
    }
    __syncthreads();
    s = buf[0][0]; ss = buf[0][1];

    float invC = 1.f / (float)C;
    float mu = s * invC;
    float var = ss * invC - mu * mu;
    float inv = rsqrtf(var + 1e-5f);
    for (int i = threadIdx.x; i < C; i += 256) {
        yr[i] = __float2bfloat16((xr[i] - mu) * inv * g[i] + b[i]);
    }
}

// ---------------- LayerNorm: bf16 in -> bf16 out (in place ok) ----------------
__global__ __launch_bounds__(256) void ln_bf16_kernel(
    const __hip_bfloat16* __restrict__ x, const float* __restrict__ g,
    const float* __restrict__ b, __hip_bfloat16* __restrict__ y, int C)
{
    int row = blockIdx.x;
    const __hip_bfloat16* xr = x + (long)row * C;
    __hip_bfloat16* yr = y + (long)row * C;

    float s = 0.f, ss = 0.f;
    for (int i = threadIdx.x; i < C; i += 256) {
        float v = __bfloat162float(xr[i]);
        s += v; ss += v * v;
    }
    #pragma unroll
    for (int d = 32; d; d >>= 1) {
        s  += __shfl_down(s, d);
        ss += __shfl_down(ss, d);
    }
    __shared__ float buf[4][2];
    int wid = threadIdx.x >> 6, lane = threadIdx.x & 63;
    if (lane == 0) { buf[wid][0] = s; buf[wid][1] = ss; }
    __syncthreads();
    if (threadIdx.x == 0) {
        s = buf[0][0] + buf[1][0] + buf[2][0] + buf[3][0];
        ss = buf[0][1] + buf[1][1] + buf[2][1] + buf[3][1];
        buf[0][0] = s; buf[0][1] = ss;
    }
    __syncthreads();
    s = buf[0][0]; ss = buf[0][1];

    float invC = 1.f / (float)C;
    float mu = s * invC;
    float var = ss * invC - mu * mu;
    float inv = rsqrtf(var + 1e-5f);
    for (int i = threadIdx.x; i < C; i += 256) {
        float v = __bfloat162float(xr[i]);
        yr[i] = __float2bfloat16((v - mu) * inv * g[i] + b[i]);
    }
}

// ---------------- bf16 MFMA GEMM, swizzled + distance-2 pipeline ----------
// C = A[M,K] @ W[N,K]^T (+bias)(+gelu-erf)(+residual)
// Tile 128 x TN, BK=32, 256 threads = 4 waves.
template <int TN>
__global__ __launch_bounds__(256, 3) void gemm_mfma(
    const __hip_bfloat16* __restrict__ A,
    const __hip_bfloat16* __restrict__ W,
    const float* __restrict__ bias, const float* __restrict__ residual,
    void* __restrict__ Cout, int M, int N, int K, int act, int out_bf16)
{
    constexpr int WN = (TN == 128) ? 2 : 1;
    constexpr int WM = 4 / WN;              // 2 or 4
    constexpr int FJ = 4;
    constexpr int FI = 128 / (WM * 16);     // 4 or 2

    __shared__ __hip_bfloat16 Asl[2][128 * 32];
    __shared__ __hip_bfloat16 Bsl[2][TN * 32];

    int tid = threadIdx.x;
    int wave = tid >> 6, lane = tid & 63;

    // XCD-compact swizzle: dispatch is x-fastest linear, XCD = lin % 8.
    // Give XCD x the M-tile band [x*chunk, (x+1)*chunk), n-major inside.
    int mt, nt;
    {
        int gx = gridDim.x, gy = gridDim.y;
        int lin = blockIdx.y * gx + blockIdx.x;
        if ((gy & 7) == 0) {
            int chunk = gy >> 3;
            int xcd = lin & 7, q = lin >> 3;
            mt = xcd * chunk + (q % chunk);
            nt = q / chunk;
        } else { mt = blockIdx.y; nt = blockIdx.x; }
    }
    int bm = mt * 128, bn = nt * TN;
    int wm = wave & (WM - 1), wn = wave / WM;
    int fm = lane & 15, quad = lane >> 4;

    int srow = lane >> 2;          // 0..15
    int skk  = (lane & 3) * 8;     // 0,8,16,24 (bf16 elems)

    const __hip_bfloat16* Ap = A + (long)(bm + wave * 16 + srow) * K + skk;
    const __hip_bfloat16* Bp = W + (long)(bn + wave * 16 + srow) * K + skk;
    const long a64 = (long)64 * K;

    const int nk = K / 32;          // 32 or 128 (even, >=4)
    floatx4 acc[FI][FJ] = {};
    const int aoff = (wave * 16 + srow) * 32 + skk;

    // two explicit register slots (A/B), no dynamic indexing
    uint4 a0A, a1A, b0A, b1A;
    uint4 a0B, a1B, b0B, b1B;

#define GLOADA(t) { const long o = (long)(t) * 32; \
    a0A = *(const uint4*)(Ap + o); a1A = *(const uint4*)(Ap + a64 + o); \
    b0A = *(const uint4*)(Bp + o); if (TN == 128) b1A = *(const uint4*)(Bp + a64 + o); }
#define GLOADB(t) { const long o = (long)(t) * 32; \
    a0B = *(const uint4*)(Ap + o); a1B = *(const uint4*)(Ap + a64 + o); \
    b0B = *(const uint4*)(Bp + o); if (TN == 128) b1B = *(const uint4*)(Bp + a64 + o); }
#define LWRITEA(bf) { *(uint4*)&Asl[bf][aoff] = a0A; *(uint4*)&Asl[bf][aoff + 2048] = a1A; \
    *(uint4*)&Bsl[bf][aoff] = b0A; if (TN == 128) *(uint4*)&Bsl[bf][aoff + 2048] = b1A; }
#define LWRITEB(bf) { *(uint4*)&Asl[bf][aoff] = a0B; *(uint4*)&Asl[bf][aoff + 2048] = a1B; \
    *(uint4*)&Bsl[bf][aoff] = b0B; if (TN == 128) *(uint4*)&Bsl[bf][aoff + 2048] = b1B; }

    auto compute = [&](int buf) {
        const __hip_bfloat16* Ab = Asl[buf];
        const __hip_bfloat16* Bb = Bsl[buf];
        short8 bfr[FJ];
        #pragma unroll
        for (int j = 0; j < FJ; ++j)
            bfr[j] = *(const short8*)(Bb + (wn * 64 + j * 16 + fm) * 32 + quad * 8);
        #pragma unroll
        for (int i = 0; i < FI; ++i) {
            short8 af = *(const short8*)(Ab + (wm * FI * 16 + i * 16 + fm) * 32 + quad * 8);
            #pragma unroll
            for (int j = 0; j < FJ; ++j)
                acc[i][j] = __builtin_amdgcn_mfma_f32_16x16x32_bf16(
                    af, bfr[j], acc[i][j], 0, 0, 0);
        }
    };

    // prologue: T0->slotA->buf0, T1->slotB, T2->slotA (after write of T0)
    GLOADA(0); GLOADB(1);
    LWRITEA(0);
    GLOADA(2);
    __syncthreads();

    for (int kt = 0; kt < nk; kt += 2) {
        compute(0);                       // tile kt
        LWRITEB(1);                       // tile kt+1 -> buf1
        if (kt + 3 < nk) GLOADB(kt + 3);
        __syncthreads();
        compute(1);                       // tile kt+1
        if (kt + 2 < nk) {
            LWRITEA(0);                   // tile kt+2 -> buf0
            if (kt + 4 < nk) GLOADA(kt + 4);
        }
        __syncthreads();
    }
#undef GLOADA
#undef GLOADB
#undef LWRITEA
#undef LWRITEB

    int mbase = bm + wm * FI * 16;
    int nbase = bn + wn * 64;
    #pragma unroll
    for (int i = 0; i < FI; ++i) {
        #pragma unroll
        for (int j = 0; j < FJ; ++j) {
            int ncol = nbase + j * 16 + fm;
            #pragma unroll
            for (int r = 0; r < 4; ++r) {
                int mrow = mbase + i * 16 + quad * 4 + r;
                float v = acc[i][j][r];
                if (bias) v += bias[ncol];
                if (act == 1) v = 0.5f * v * (1.f + erff(v * 0.70710678118654752f));
                if (residual) v += residual[(long)mrow * N + ncol];
                if (out_bf16)
                    ((__hip_bfloat16*)Cout)[(long)mrow * N + ncol] = __float2bfloat16(v);
                else
                    ((float*)Cout)[(long)mrow * N + ncol] = v;
            }
        }
    }
}

// ---------------- MFMA flash attention, pipelined ----------------
// 64 queries (4 waves x 16) per block; 16 blocks per (b,h); XCD swizzle:
// xcd owns 8 (b,h) pairs (K/V 2 MB, L2-resident). Double-buffered K/V LDS,
// one barrier per key-tile; K/V(kt+1) gloaded right after the barrier.
__global__ __launch_bounds__(256) void attn_mfma(
    const __hip_bfloat16* __restrict__ qkv, __hip_bfloat16* __restrict__ o_out)
{
    __shared__ __align__(16) char Ks[2][64 * 144];
    __shared__ __align__(16) char Vt[2][64 * 144];
    __shared__ __align__(16) char Ps[4 * 16 * 144];

    const int C3 = 3 * CDIM;
    int lin = blockIdx.x;
    int xcd = lin & 7, q = lin >> 3;           // q in [0,128)
    int bh = xcd * 8 + (q >> 4);               // 8 bh per xcd
    int qt = q & 15;
    int b = bh >> 4, hh = bh & 15;
    int tid = threadIdx.x, wave = tid >> 6, lane = tid & 63;
    int l = lane & 15, quad = lane >> 4;

    const __hip_bfloat16* qrow =
        qkv + (long)(b * 1024 + qt * 64 + wave * 16 + l) * C3 + hh * DHEAD;
    short8 qf0 = *(const short8*)(qrow + quad * 8);
    short8 qf1 = *(const short8*)(qrow + 32 + quad * 8);

    char* Psw = Ps + wave * (16 * 144);

    int sc = tid & 7;          // 16B d-chunk
    int skl = tid >> 3;        // 0..31

    const __hip_bfloat16* Kbase = qkv + (long)(b * 1024) * C3 + CDIM + hh * DHEAD;
    const __hip_bfloat16* Vbase = qkv + (long)(b * 1024) * C3 + 2 * CDIM + hh * DHEAD;
    const int kpp = skl ^ (sc << 2);

    floatx4 facc[4] = {};
    float mrun = -1e30f, lrun = 0.f;

    uint4 kA0, kA1, vA0, vA1;   // slot A
    uint4 kB0, kB1, vB0, vB1;   // slot B

#define GKV(t, k0, k1, v0, v1) { \
    const __hip_bfloat16* Kg = Kbase + (long)((t) * 64) * C3; \
    const __hip_bfloat16* Vg = Vbase + (long)((t) * 64) * C3; \
    k0 = *(const uint4*)(Kg + (long)skl * C3 + sc * 8); \
    k1 = *(const uint4*)(Kg + (long)(skl + 32) * C3 + sc * 8); \
    v0 = *(const uint4*)(Vg + (long)(2 * skl) * C3 + sc * 8); \
    v1 = *(const uint4*)(Vg + (long)(2 * skl + 1) * C3 + sc * 8); }
#define WKV(bf, k0, k1, v0, v1) { \
    *(uint4*)(Ks[bf] + skl * 144 + sc * 16) = k0; \
    *(uint4*)(Ks[bf] + (skl + 32) * 144 + sc * 16) = k1; \
    const ushort* e0 = (const ushort*)&v0; \
    const ushort* e1 = (const ushort*)&v1; \
    _Pragma("unroll") \
    for (int j = 0; j < 8; ++j) { \
        unsigned dw = (unsigned)e0[j] | ((unsigned)e1[j] << 16); \
        *(unsigned*)(Vt[bf] + (sc * 8 + j) * 144 + kpp * 4) = dw; \
    } }

    auto compute = [&](int buf) {
        floatx4 st[4] = {};
        #pragma unroll
        for (int kb = 0; kb < 4; ++kb) {
            short8 k0 = *(const short8*)(Ks[buf] + (kb * 16 + l) * 144 + quad * 16);
            short8 k1 = *(const short8*)(Ks[buf] + (kb * 16 + l) * 144 + 64 + quad * 16);
            st[kb] = __builtin_amdgcn_mfma_f32_16x16x32_bf16(k0, qf0, st[kb], 0, 0, 0);
            st[kb] = __builtin_amdgcn_mfma_f32_16x16x32_bf16(k1, qf1, st[kb], 0, 0, 0);
        }
        float p[16];
        float tm = -1e30f;
        #pragma unroll
        for (int kb = 0; kb < 4; ++kb)
            #pragma unroll
            for (int r = 0; r < 4; ++r) {
                float s = st[kb][r] * 0.125f;
                p[kb * 4 + r] = s;
                tm = fmaxf(tm, s);
            }
        tm = fmaxf(tm, __shfl_xor(tm, 16));
        tm = fmaxf(tm, __shfl_xor(tm, 32));
        float mn = fmaxf(mrun, tm);
        float alpha = __expf(mrun - mn);
        float psum = 0.f;
        #pragma unroll
        for (int i = 0; i < 16; ++i) { p[i] = __expf(p[i] - mn); psum += p[i]; }
        psum += __shfl_xor(psum, 16);
        psum += __shfl_xor(psum, 32);
        lrun = lrun * alpha + psum;
        mrun = mn;

        #pragma unroll
        for (int kb = 0; kb < 4; ++kb) {
            __hip_bfloat16 t[4];
            #pragma unroll
            for (int r = 0; r < 4; ++r) t[r] = __float2bfloat16(p[kb * 4 + r]);
            *(uint2*)(Psw + l * 144 + kb * 32 + quad * 8) = *(const uint2*)t;
        }

        float a0 = __shfl(alpha, quad * 4 + 0);
        float a1 = __shfl(alpha, quad * 4 + 1);
        float a2 = __shfl(alpha, quad * 4 + 2);
        float a3 = __shfl(alpha, quad * 4 + 3);
        #pragma unroll
        for (int db = 0; db < 4; ++db) {
            facc[db][0] *= a0; facc[db][1] *= a1;
            facc[db][2] *= a2; facc[db][3] *= a3;
        }

        short8 pf0 = *(const short8*)(Psw + l * 144 + quad * 16);
        short8 pf1 = *(const short8*)(Psw + l * 144 + 64 + quad * 16);
        #pragma unroll
        for (int db = 0; db < 4; ++db) {
            int d = db * 16 + l;
            int o3 = (d >> 3) & 7;
            short8 v0 = *(const short8*)(Vt[buf] + d * 144 + ((quad ^ o3) << 4));
            short8 v1 = *(const short8*)(Vt[buf] + d * 144 + (((4 + quad) ^ o3) << 4));
            facc[db] = __builtin_amdgcn_mfma_f32_16x16x32_bf16(pf0, v0, facc[db], 0, 0, 0);
            facc[db] = __builtin_amdgcn_mfma_f32_16x16x32_bf16(pf1, v1, facc[db], 0, 0, 0);
        }
    };

    GKV(0, kA0, kA1, vA0, vA1);
    #pragma unroll 1
    for (int kt = 0; kt < 16; kt += 2) {
        WKV(0, kA0, kA1, vA0, vA1);            // tile kt -> buf0
        __syncthreads();
        GKV(kt + 1, kB0, kB1, vB0, vB1);       // prefetch kt+1
        compute(0);
        WKV(1, kB0, kB1, vB0, vB1);            // tile kt+1 -> buf1
        __syncthreads();
        if (kt + 2 < 16) GKV(kt + 2, kA0, kA1, vA0, vA1);
        compute(1);
    }
#undef GKV
#undef WKV

    float il0 = 1.f / __shfl(lrun, quad * 4 + 0);
    float il1 = 1.f / __shfl(lrun, quad * 4 + 1);
    float il2 = 1.f / __shfl(lrun, quad * 4 + 2);
    float il3 = 1.f / __shfl(lrun, quad * 4 + 3);
    __hip_bfloat16* orow =
        o_out + (long)(b * 1024 + qt * 64 + wave * 16) * CDIM + hh * DHEAD;
    #pragma unroll
    for (int db = 0; db < 4; ++db) {
        int col = db * 16 + l;
        orow[(quad * 4 + 0) * CDIM + col] = __float2bfloat16(facc[db][0] * il0);
        orow[(quad * 4 + 1) * CDIM + col] = __float2bfloat16(facc[db][1] * il1);
        orow[(quad * 4 + 2) * CDIM + col] = __float2bfloat16(facc[db][2] * il2);
        orow[(quad * 4 + 3) * CDIM + col] = __float2bfloat16(facc[db][3] * il3);
    }
}

// ---------------------------------------------------------------------------
extern "C" void kernel_launch(void* const* d_in, const int* in_sizes, int n_in,
                              void* d_out, int out_size, void* d_ws, size_t ws_size,
                              hipStream_t stream)
{
    const float* x      = (const float*)d_in[0];
    const float* qkv_w  = (const float*)d_in[1];
    const float* proj_w = (const float*)d_in[2];
    const float* proj_b = (const float*)d_in[3];
    const float* fc1_w  = (const float*)d_in[4];
    const float* fc1_b  = (const float*)d_in[5];
    const float* fc2_w  = (const float*)d_in[6];
    const float* fc2_b  = (const float*)d_in[7];
    const float* ln1_g  = (const float*)d_in[8];
    const float* ln1_b  = (const float*)d_in[9];
    const float* ln2_g  = (const float*)d_in[10];
    const float* ln2_b  = (const float*)d_in[11];
    const float* lnh_g  = (const float*)d_in[12];
    const float* lnh_b  = (const float*)d_in[13];

    float* out = (float*)d_out;

    __hip_bfloat16* wsb     = (__hip_bfloat16*)d_ws;
    __hip_bfloat16* qkvw_bf = wsb;
    __hip_bfloat16* fc1w_bf = qkvw_bf + 3l * 1024 * 1024;
    __hip_bfloat16* fc2w_bf = fc1w_bf + 4l * 1024 * 1024;
    __hip_bfloat16* projw_bf= fc2w_bf + 4l * 1024 * 1024;
    __hip_bfloat16* h_bf    = projw_bf + 1l * 1024 * 1024;
    __hip_bfloat16* qkv_bf  = h_bf + 4l * 1024 * 1024;
    __hip_bfloat16* o_bf    = qkv_bf + 12l * 1024 * 1024;
    __hip_bfloat16* u_bf    = o_bf + 4l * 1024 * 1024;

    // 0. all weights fp32 -> bf16
    cvt_all<<<12288, 256, 0, stream>>>(qkv_w, fc1_w, fc2_w, proj_w, qkvw_bf);

    // 1. h = LN1(x)
    ln_f32_kernel<<<TOKENS, 256, 0, stream>>>(x, ln1_g, ln1_b, h_bf, CDIM);
    // 2. qkv = h @ qkv_w^T
    gemm_mfma<128><<<dim3(3072 / 128, TOKENS / 128), 256, 0, stream>>>(
        h_bf, qkvw_bf, nullptr, nullptr, qkv_bf, TOKENS, 3072, CDIM, 0, 1);
    // 3. o = attention(qkv)
    attn_mfma<<<1024, 256, 0, stream>>>(qkv_bf, o_bf);
    // 4. out = x + o @ proj_w^T + proj_b
    gemm_mfma<64><<<dim3(CDIM / 64, TOKENS / 128), 256, 0, stream>>>(
        o_bf, projw_bf, proj_b, x, out, TOKENS, CDIM, CDIM, 0, 0);
    // 5. h2 = LN2(out)
    ln_f32_kernel<<<TOKENS, 256, 0, stream>>>(out, ln2_g, ln2_b, h_bf, CDIM);
    // 6. u = gelu(h2 @ fc1_w^T + fc1_b)
    gemm_mfma<128><<<dim3(HID / 128, TOKENS / 128), 256, 0, stream>>>(
        h_bf, fc1w_bf, fc1_b, nullptr, u_bf, TOKENS, HID, CDIM, 1, 1);
    // 7. u = LNh(u) in place
    ln_bf16_kernel<<<TOKENS, 256, 0, stream>>>(u_bf, lnh_g, lnh_b, u_bf, HID);
    // 8. out = out + u @ fc2_w^T + fc2_b
    gemm_mfma<64><<<dim3(CDIM / 64, TOKENS / 128), 256, 0, stream>>>(
        u_bf, fc2w_bf, fc2_b, out, out, TOKENS, CDIM, HID, 0, 0);
}